// Round 11
// baseline (1297.456 us; speedup 1.0000x reference)
//
#include <hip/hip_runtime.h>
#include <hip/hip_bf16.h>
#include <stdint.h>

// Problem dims
#define B_SZ 32
#define T_SZ 512
#define I_SZ 1024
#define H_SZ 8
#define HS_SZ 128

typedef __attribute__((ext_vector_type(8))) short short8;
typedef __attribute__((ext_vector_type(4))) float f32x4;

// ---------------- fp32 <-> bf16 helpers ----------------
static __device__ __forceinline__ unsigned short f2bf(float f) {
  union { float f; unsigned int u; } c; c.f = f;
  unsigned int u = c.u;
  unsigned int r = (u + 0x7fffu + ((u >> 16) & 1u)) >> 16;
  return (unsigned short)r;
}
static __device__ __forceinline__ float bf2f(unsigned short s) {
  union { unsigned int u; float f; } c; c.u = ((unsigned int)s) << 16;
  return c.f;
}
static __device__ __forceinline__ void split2(float x, unsigned short& hi,
                                              unsigned short& lo) {
  hi = f2bf(x);
  lo = f2bf(x - bf2f(hi));
}

__global__ void conv_x_split(const float* __restrict__ x,
                             unsigned short* __restrict__ ohi,
                             unsigned short* __restrict__ olo, int n4) {
  int i = blockIdx.x * blockDim.x + threadIdx.x;
  if (i >= n4) return;
  float4 v = ((const float4*)x)[i];
  ushort4 h, l;
  split2(v.x, h.x, l.x);
  split2(v.y, h.y, l.y);
  split2(v.z, h.z, l.z);
  split2(v.w, h.w, l.w);
  ((ushort4*)ohi)[i] = h;
  ((ushort4*)olo)[i] = l;
}

// Combined weight Wc[4096][1024], row n = h*512 + k4:
//   k4 in [0,256)   -> weight_if[h][k4][:]      (i rows then f rows)
//   k4 in [256,512) -> weight_zo[h][k4-256][:]  (z rows then o rows)
__global__ void conv_w_split(const float* __restrict__ wif,
                             const float* __restrict__ wzo,
                             unsigned short* __restrict__ ohi,
                             unsigned short* __restrict__ olo) {
  int i = blockIdx.x * blockDim.x + threadIdx.x;  // float4 index
  int flat = i * 4;
  int n = flat >> 10;
  int col = flat & 1023;
  int h = n >> 9, k4 = n & 511;
  const float* src = (k4 < 256)
                         ? (wif + ((size_t)(h * 256 + k4) * 1024 + col))
                         : (wzo + ((size_t)(h * 256 + (k4 - 256)) * 1024 + col));
  float4 v = *(const float4*)src;
  ushort4 hh, ll;
  split2(v.x, hh.x, ll.x);
  split2(v.y, hh.y, ll.y);
  split2(v.z, hh.z, ll.z);
  split2(v.w, hh.w, ll.w);
  ((ushort4*)ohi)[i] = hh;
  ((ushort4*)olo)[i] = ll;
}

// ---------------- GEMM (round-9 structure, unchanged) ----------------
__device__ __forceinline__ void gld_lds16(const void* g, void* l) {
  __builtin_amdgcn_global_load_lds(
      (const __attribute__((address_space(1))) void*)g,
      (__attribute__((address_space(3))) void*)l, 16, 0, 0);
}

__global__ __launch_bounds__(512)
void gemm3_kernel(const unsigned short* __restrict__ Ahi,
                  const unsigned short* __restrict__ Alo,
                  const unsigned short* __restrict__ Whi,
                  const unsigned short* __restrict__ Wlo,
                  float* __restrict__ G, int t0, int ltch) {
  __shared__ short lds2[2][24576];  // 2 x 48 KB

  const int tid = threadIdx.x;
  const int lane = tid & 63, wv = tid >> 6;
  const int wm = wv >> 1, wn = wv & 1;   // 4 M-waves x 2 N-waves
  const int bx = blockIdx.x, by = blockIdx.y;
  const int l15 = lane & 15, kg = lane >> 4;
  const int tchm = (1 << ltch) - 1;

  const unsigned short* gsrc[6];
#pragma unroll
  for (int t = 0; t < 6; ++t) {
    int u = tid + t * 512;
    int j = u & 3;
    if (t < 4) {
      int r = (u >> 2) & 255;
      int gslot = j ^ ((r >> 1) & 3);
      int cr = bx * 256 + r;
      size_t xsrow = (size_t)(cr >> ltch) * 512 + t0 + (cr & tchm);
      gsrc[t] = ((t < 2) ? Ahi : Alo) + xsrow * 1024 + gslot * 8;
    } else {
      int r = (u >> 2) & 127;
      int gslot = j ^ ((r >> 1) & 3);
      size_t wr = (size_t)by * 128 + r;
      gsrc[t] = ((t == 4) ? Whi : Wlo) + wr * 1024 + gslot * 8;
    }
  }

  int offa[4], offw[4];
#pragma unroll
  for (int mi = 0; mi < 4; ++mi) {
    int r = wm * 64 + mi * 16 + l15;
    offa[mi] = r * 32 + (kg ^ ((r >> 1) & 3)) * 8;
  }
#pragma unroll
  for (int ni = 0; ni < 4; ++ni) {
    int r = wn * 64 + ni * 16 + l15;
    offw[ni] = r * 32 + (kg ^ ((r >> 1) & 3)) * 8;
  }

  f32x4 zero4 = {0.f, 0.f, 0.f, 0.f};
  f32x4 acc[4][4];
#pragma unroll
  for (int mi = 0; mi < 4; ++mi)
#pragma unroll
    for (int ni = 0; ni < 4; ++ni) acc[mi][ni] = zero4;

#pragma unroll
  for (int t = 0; t < 6; ++t)
    gld_lds16(gsrc[t], &lds2[0][(wv * 64 + t * 512) * 8]);
#pragma unroll
  for (int t = 0; t < 6; ++t)
    gld_lds16(gsrc[t] + 32, &lds2[1][(wv * 64 + t * 512) * 8]);
  asm volatile("s_waitcnt vmcnt(6)" : : : "memory");
  __builtin_amdgcn_s_barrier();

  for (int ks = 0; ks < 32; ++ks) {
    const short* bp = &lds2[ks & 1][0];

    short8 ah[4], wh4[4], al[4], wl4[4];
#pragma unroll
    for (int mi = 0; mi < 4; ++mi) ah[mi] = *(const short8*)(bp + offa[mi]);
#pragma unroll
    for (int ni = 0; ni < 4; ++ni)
      wh4[ni] = *(const short8*)(bp + 16384 + offw[ni]);

    __builtin_amdgcn_s_setprio(1);
#pragma unroll
    for (int mi = 0; mi < 4; ++mi)
#pragma unroll
      for (int ni = 0; ni < 4; ++ni)
        acc[mi][ni] = __builtin_amdgcn_mfma_f32_16x16x32_bf16(
            ah[mi], wh4[ni], acc[mi][ni], 0, 0, 0);

#pragma unroll
    for (int mi = 0; mi < 4; ++mi)
      al[mi] = *(const short8*)(bp + 8192 + offa[mi]);
#pragma unroll
    for (int mi = 0; mi < 4; ++mi)
#pragma unroll
      for (int ni = 0; ni < 4; ++ni)
        acc[mi][ni] = __builtin_amdgcn_mfma_f32_16x16x32_bf16(
            al[mi], wh4[ni], acc[mi][ni], 0, 0, 0);

#pragma unroll
    for (int ni = 0; ni < 4; ++ni)
      wl4[ni] = *(const short8*)(bp + 20480 + offw[ni]);
#pragma unroll
    for (int mi = 0; mi < 4; ++mi)
#pragma unroll
      for (int ni = 0; ni < 4; ++ni)
        acc[mi][ni] = __builtin_amdgcn_mfma_f32_16x16x32_bf16(
            ah[mi], wl4[ni], acc[mi][ni], 0, 0, 0);
    __builtin_amdgcn_s_setprio(0);

    asm volatile("s_waitcnt lgkmcnt(0)" : : : "memory");
    __builtin_amdgcn_sched_barrier(0);
    __builtin_amdgcn_s_barrier();

    if (ks + 2 < 32) {
#pragma unroll
      for (int t = 0; t < 6; ++t)
        gld_lds16(gsrc[t] + (ks + 2) * 32,
                  &lds2[ks & 1][(wv * 64 + t * 512) * 8]);
      asm volatile("s_waitcnt vmcnt(6)" : : : "memory");
    } else {
      asm volatile("s_waitcnt vmcnt(0)" : : : "memory");
    }
    __builtin_amdgcn_s_barrier();
  }

#pragma unroll
  for (int mi = 0; mi < 4; ++mi)
#pragma unroll
    for (int ni = 0; ni < 4; ++ni)
#pragma unroll
      for (int r = 0; r < 4; ++r) {
        int grow = bx * 256 + wm * 64 + mi * 16 + kg * 4 + r;
        int gcol = by * 128 + wn * 64 + ni * 16 + l15;
        G[(size_t)grow * 4096 + gcol] = acc[mi][ni][r];
      }
}

// ---------------- Recurrence (round 11: MFMA over batch) ----------------
// 16 blocks = 2 b-groups (16 b each) x 8 heads; 512 threads (8 waves).
// Per step per head-group: lin[16b x 512] = h[16b x 128] . W_hh^T via
// mfma_16x16x32_bf16, 3-pass split-bf16 (hh + lo.h + hi.lo), acc f32 —
// same arithmetic budget as the main GEMM. Wave w owns e-window
// [16w,16w+16) and gate tiles {i,f,z,o} at rows gt*128+e, so the gate
// combine is LANE-LOCAL: D[row b=(lane>>4)*4+r][col e=16w+(lane&15)]
// (m89 layout, proven by gemm3 in this session). W_hh B-frags are loaded
// once into registers (128 VGPRs) and consumed natively by MFMA (no
// accvgpr moves — round-10 lesson). h is re-split to bf16 hi/lo each step
// into a 16 KB double-buffered LDS tile, XOR-swizzled:
//   unit(ks,kq; b) = ((ks ^ (b>>2)) & 3)*4 + ((kq ^ (b&3)) & 3)
// (round-trip verified; <=2-way banks). One barrier/step; acc is C-in
// initialized with bias+G so gates read preactivations from the
// accumulator; G prefetched +1 step.
__global__ __launch_bounds__(512, 1)
void recur2_kernel(const float* __restrict__ G,     // [32*tch, 4096] chunk
                   const float* __restrict__ Whh,   // [8,512,128]
                   const float* __restrict__ bias,  // [8,512]
                   float* __restrict__ out,         // [32,512,1024]
                   float* __restrict__ state,       // 4 x [32,8,128]
                   int t0, int tch, int first) {
  const int blk = blockIdx.x;          // 0..15
  const int g16 = (blk >> 3) * 16;     // batch-group base (0 or 16)
  const int h = blk & 7;
  const int t = threadIdx.x;
  const int w = t >> 6, l = t & 63;
  const int l15 = l & 15, kg = l >> 4;
  const int e = w * 16 + l15;          // element column this lane covers

  __shared__ __align__(16) short hb[2][2][2048];  // [buf][hi/lo][16b x 128k]

  // ---- W_hh B-frags (load once; split hi/lo) ----
  // wh[gt][ks]: lane l -> W[h][gt*128 + e][ks*32 + kg*8 + j], j=0..7
  short8 wh[4][4], wl[4][4];
#pragma unroll
  for (int gt = 0; gt < 4; ++gt)
#pragma unroll
    for (int ks = 0; ks < 4; ++ks) {
      const float* wp = Whh + (size_t)h * 65536 +
                        (size_t)(gt * 128 + e) * 128 + ks * 32 + kg * 8;
      float4 v0 = ((const float4*)wp)[0];
      float4 v1 = ((const float4*)wp)[1];
      float vv[8] = {v0.x, v0.y, v0.z, v0.w, v1.x, v1.y, v1.z, v1.w};
      short8 hi8, lo8;
#pragma unroll
      for (int j = 0; j < 8; ++j) {
        unsigned short hi, lo;
        split2(vv[j], hi, lo);
        hi8[j] = (short)hi;
        lo8[j] = (short)lo;
      }
      wh[gt][ks] = hi8;
      wl[gt][ks] = lo8;
    }

  float bj[4];
#pragma unroll
  for (int gt = 0; gt < 4; ++gt) bj[gt] = bias[h * 512 + gt * 128 + e];

  // ---- per-(b,e) addresses; b = kg*4 + r ----
  size_t gbase_r[4], obase_r[4];
  int sibase_r[4], woff[4];
  const int u = e >> 3;  // 16B unit within the 128-k row
#pragma unroll
  for (int r = 0; r < 4; ++r) {
    int b = kg * 4 + r;
    gbase_r[r] = ((size_t)(g16 + b) * tch) * 4096 + h * 512 + e;
    obase_r[r] = ((size_t)(g16 + b) * 512 + t0) * 1024 + h * 128 + e;
    sibase_r[r] = ((g16 + b) * 8 + h) * 128 + e;
    woff[r] = b * 128 +
              (((((u >> 2) ^ kg) & 3) << 2) | (((u & 3) ^ r) & 3)) * 8 +
              (e & 7);
  }
  // A-frag read offsets (row = l15 = b), per k-step
  int roA[4];
#pragma unroll
  for (int ks = 0; ks < 4; ++ks)
    roA[ks] = l15 * 128 +
              ((((ks ^ (l15 >> 2)) & 3) << 2) | ((kg ^ l15) & 3)) * 8;

  // ---- state init + stage h(0) into buf 0 ----
  float c_r[4] = {0.f, 0.f, 0.f, 0.f};
  float n_r[4] = {0.f, 0.f, 0.f, 0.f};
  float m_r[4] = {0.f, 0.f, 0.f, 0.f};
  short* buf0 = &hb[0][0][0];
#pragma unroll
  for (int r = 0; r < 4; ++r) {
    float h0 = 0.f;
    if (!first) {
      h0 = state[sibase_r[r]];
      c_r[r] = state[32768 + sibase_r[r]];
      m_r[r] = state[65536 + sibase_r[r]];
      n_r[r] = state[98304 + sibase_r[r]];
    }
    unsigned short hhi, hlo;
    split2(h0, hhi, hlo);
    buf0[woff[r]] = (short)hhi;
    buf0[2048 + woff[r]] = (short)hlo;
  }

  // G(0) preload
  f32x4 gc[4];
#pragma unroll
  for (int gt = 0; gt < 4; ++gt)
#pragma unroll
    for (int r = 0; r < 4; ++r) gc[gt][r] = G[gbase_r[r] + gt * 128];

  __syncthreads();

  for (int s = 0; s < tch; ++s) {
    const short* bufr = &hb[s & 1][0][0];
    short8 ahf[4], alf[4];
#pragma unroll
    for (int ks = 0; ks < 4; ++ks) {
      ahf[ks] = *(const short8*)(bufr + roA[ks]);
      alf[ks] = *(const short8*)(bufr + 2048 + roA[ks]);
    }

    // prefetch G(s+1) — consumed after the MFMA+gate phases
    f32x4 gn[4];
#pragma unroll
    for (int gt = 0; gt < 4; ++gt) {
      f32x4 z = {0.f, 0.f, 0.f, 0.f};
      gn[gt] = z;
    }
    if (s + 1 < tch) {
#pragma unroll
      for (int gt = 0; gt < 4; ++gt)
#pragma unroll
        for (int r = 0; r < 4; ++r)
          gn[gt][r] = G[gbase_r[r] + (size_t)(s + 1) * 4096 + gt * 128];
    }

    // acc C-in = bias + G(s)
    f32x4 acc[4];
#pragma unroll
    for (int gt = 0; gt < 4; ++gt)
#pragma unroll
      for (int r = 0; r < 4; ++r) acc[gt][r] = bj[gt] + gc[gt][r];

    __builtin_amdgcn_s_setprio(1);
#pragma unroll
    for (int gt = 0; gt < 4; ++gt)
#pragma unroll
      for (int ks = 0; ks < 4; ++ks)
        acc[gt] = __builtin_amdgcn_mfma_f32_16x16x32_bf16(
            ahf[ks], wh[gt][ks], acc[gt], 0, 0, 0);
#pragma unroll
    for (int gt = 0; gt < 4; ++gt)
#pragma unroll
      for (int ks = 0; ks < 4; ++ks)
        acc[gt] = __builtin_amdgcn_mfma_f32_16x16x32_bf16(
            alf[ks], wh[gt][ks], acc[gt], 0, 0, 0);
#pragma unroll
    for (int gt = 0; gt < 4; ++gt)
#pragma unroll
      for (int ks = 0; ks < 4; ++ks)
        acc[gt] = __builtin_amdgcn_mfma_f32_16x16x32_bf16(
            ahf[ks], wl[gt][ks], acc[gt], 0, 0, 0);
    __builtin_amdgcn_s_setprio(0);

    // ---- gate (lane-local i/f/z/o) + h split-write to buf[(s+1)&1] ----
    short* bufw = &hb[(s + 1) & 1][0][0];
#pragma unroll
    for (int r = 0; r < 4; ++r) {
      float iv = acc[0][r];
      float fv = acc[1][r];
      float zv = acc[2][r];
      float ov = acc[3][r];
      float e2 = __expf(2.f * zv);
      float zt = 1.f - 2.f * __builtin_amdgcn_rcpf(e2 + 1.f);  // tanh
      float og = __builtin_amdgcn_rcpf(1.f + __expf(-ov));     // sigmoid
      float mn = fmaxf(fv + m_r[r], iv);
      float ie = __expf(iv - mn);
      float fe = __expf(fv + m_r[r] - mn);
      c_r[r] = fe * c_r[r] + ie * zt;
      n_r[r] = fe * n_r[r] + ie;
      m_r[r] = mn;
      float hnew = og * c_r[r] * __builtin_amdgcn_rcpf(n_r[r]);
      out[obase_r[r] + (size_t)s * 1024] = hnew;
      unsigned short hhi, hlo;
      split2(hnew, hhi, hlo);
      bufw[woff[r]] = (short)hhi;
      bufw[2048 + woff[r]] = (short)hlo;
    }
#pragma unroll
    for (int gt = 0; gt < 4; ++gt) gc[gt] = gn[gt];
    __syncthreads();
  }

#pragma unroll
  for (int r = 0; r < 4; ++r) {
    // recover final h from the buffer we just wrote (thread owns (b,e))
    float hfin = bf2f((unsigned short)hb[tch & 1][0][woff[r]]) +
                 bf2f((unsigned short)hb[tch & 1][1][woff[r]]);
    state[sibase_r[r]] = hfin;
    state[32768 + sibase_r[r]] = c_r[r];
    state[65536 + sibase_r[r]] = m_r[r];
    state[98304 + sibase_r[r]] = n_r[r];
  }
}

// ---------------- launch ----------------
extern "C" void kernel_launch(void* const* d_in, const int* in_sizes, int n_in,
                              void* d_out, int out_size, void* d_ws, size_t ws_size,
                              hipStream_t stream) {
  const float* xs   = (const float*)d_in[0];
  const float* wif  = (const float*)d_in[1];
  const float* wzo  = (const float*)d_in[2];
  const float* whh  = (const float*)d_in[3];
  const float* bias = (const float*)d_in[4];
  float* out = (float*)d_out;

  char* ws = (char*)d_ws;
  unsigned short* Ahi = (unsigned short*)ws;                 // 33,554,432 B
  unsigned short* Alo = (unsigned short*)(ws + 33554432);    // 33,554,432 B
  unsigned short* Whi = (unsigned short*)(ws + 67108864);    //  8,388,608 B
  unsigned short* Wlo = (unsigned short*)(ws + 75497472);    //  8,388,608 B
  const size_t gbase = 83886080;

  // adaptive time chunk so G fits in ws
  int tch = 512;
  while (tch > 8 &&
         gbase + (size_t)32 * tch * 4096 * 4 + 524288 > ws_size)
    tch >>= 1;
  int ltch = 0;
  while ((1 << (ltch + 1)) <= tch) ++ltch;

  float* G = (float*)(ws + gbase);
  float* state = (float*)(ws + gbase + (size_t)32 * tch * 4096 * 4);

  conv_x_split<<<16384, 256, 0, stream>>>(xs, Ahi, Alo, 4194304);
  conv_w_split<<<4096, 256, 0, stream>>>(wif, wzo, Whi, Wlo);

  for (int t0 = 0; t0 < 512; t0 += tch) {
    gemm3_kernel<<<dim3((32 * tch) / 256, 32), 512, 0, stream>>>(
        Ahi, Alo, Whi, Wlo, G, t0, ltch);
    recur2_kernel<<<16, 512, 0, stream>>>(G, whh, bias, out, state, t0, tch,
                                          t0 == 0);
  }
}

// Round 12
// 786.795 us; speedup vs baseline: 1.6490x; 1.6490x over previous
//
#include <hip/hip_runtime.h>
#include <hip/hip_bf16.h>
#include <stdint.h>

// Problem dims
#define B_SZ 32
#define T_SZ 512
#define I_SZ 1024
#define H_SZ 8
#define HS_SZ 128

typedef __attribute__((ext_vector_type(8))) short short8;
typedef __attribute__((ext_vector_type(4))) float f32x4;

// ---------------- fp32 <-> bf16 helpers ----------------
static __device__ __forceinline__ unsigned short f2bf(float f) {
  union { float f; unsigned int u; } c; c.f = f;
  unsigned int u = c.u;
  unsigned int r = (u + 0x7fffu + ((u >> 16) & 1u)) >> 16;
  return (unsigned short)r;
}
static __device__ __forceinline__ float bf2f(unsigned short s) {
  union { unsigned int u; float f; } c; c.u = ((unsigned int)s) << 16;
  return c.f;
}
static __device__ __forceinline__ void split2(float x, unsigned short& hi,
                                              unsigned short& lo) {
  hi = f2bf(x);
  lo = f2bf(x - bf2f(hi));
}

__global__ void conv_x_split(const float* __restrict__ x,
                             unsigned short* __restrict__ ohi,
                             unsigned short* __restrict__ olo, int n4) {
  int i = blockIdx.x * blockDim.x + threadIdx.x;
  if (i >= n4) return;
  float4 v = ((const float4*)x)[i];
  ushort4 h, l;
  split2(v.x, h.x, l.x);
  split2(v.y, h.y, l.y);
  split2(v.z, h.z, l.z);
  split2(v.w, h.w, l.w);
  ((ushort4*)ohi)[i] = h;
  ((ushort4*)olo)[i] = l;
}

// Combined weight Wc[4096][1024], row n = h*512 + k4:
//   k4 in [0,256)   -> weight_if[h][k4][:]      (i rows then f rows)
//   k4 in [256,512) -> weight_zo[h][k4-256][:]  (z rows then o rows)
__global__ void conv_w_split(const float* __restrict__ wif,
                             const float* __restrict__ wzo,
                             unsigned short* __restrict__ ohi,
                             unsigned short* __restrict__ olo) {
  int i = blockIdx.x * blockDim.x + threadIdx.x;  // float4 index
  int flat = i * 4;
  int n = flat >> 10;
  int col = flat & 1023;
  int h = n >> 9, k4 = n & 511;
  const float* src = (k4 < 256)
                         ? (wif + ((size_t)(h * 256 + k4) * 1024 + col))
                         : (wzo + ((size_t)(h * 256 + (k4 - 256)) * 1024 + col));
  float4 v = *(const float4*)src;
  ushort4 hh, ll;
  split2(v.x, hh.x, ll.x);
  split2(v.y, hh.y, ll.y);
  split2(v.z, hh.z, ll.z);
  split2(v.w, hh.w, ll.w);
  ((ushort4*)ohi)[i] = hh;
  ((ushort4*)olo)[i] = ll;
}

// ---------------- GEMM (round-9 structure, unchanged) ----------------
__device__ __forceinline__ void gld_lds16(const void* g, void* l) {
  __builtin_amdgcn_global_load_lds(
      (const __attribute__((address_space(1))) void*)g,
      (__attribute__((address_space(3))) void*)l, 16, 0, 0);
}

__global__ __launch_bounds__(512)
void gemm3_kernel(const unsigned short* __restrict__ Ahi,
                  const unsigned short* __restrict__ Alo,
                  const unsigned short* __restrict__ Whi,
                  const unsigned short* __restrict__ Wlo,
                  float* __restrict__ G, int t0, int ltch) {
  __shared__ short lds2[2][24576];  // 2 x 48 KB

  const int tid = threadIdx.x;
  const int lane = tid & 63, wv = tid >> 6;
  const int wm = wv >> 1, wn = wv & 1;   // 4 M-waves x 2 N-waves
  const int bx = blockIdx.x, by = blockIdx.y;
  const int l15 = lane & 15, kg = lane >> 4;
  const int tchm = (1 << ltch) - 1;

  const unsigned short* gsrc[6];
#pragma unroll
  for (int t = 0; t < 6; ++t) {
    int u = tid + t * 512;
    int j = u & 3;
    if (t < 4) {
      int r = (u >> 2) & 255;
      int gslot = j ^ ((r >> 1) & 3);
      int cr = bx * 256 + r;
      size_t xsrow = (size_t)(cr >> ltch) * 512 + t0 + (cr & tchm);
      gsrc[t] = ((t < 2) ? Ahi : Alo) + xsrow * 1024 + gslot * 8;
    } else {
      int r = (u >> 2) & 127;
      int gslot = j ^ ((r >> 1) & 3);
      size_t wr = (size_t)by * 128 + r;
      gsrc[t] = ((t == 4) ? Whi : Wlo) + wr * 1024 + gslot * 8;
    }
  }

  int offa[4], offw[4];
#pragma unroll
  for (int mi = 0; mi < 4; ++mi) {
    int r = wm * 64 + mi * 16 + l15;
    offa[mi] = r * 32 + (kg ^ ((r >> 1) & 3)) * 8;
  }
#pragma unroll
  for (int ni = 0; ni < 4; ++ni) {
    int r = wn * 64 + ni * 16 + l15;
    offw[ni] = r * 32 + (kg ^ ((r >> 1) & 3)) * 8;
  }

  f32x4 zero4 = {0.f, 0.f, 0.f, 0.f};
  f32x4 acc[4][4];
#pragma unroll
  for (int mi = 0; mi < 4; ++mi)
#pragma unroll
    for (int ni = 0; ni < 4; ++ni) acc[mi][ni] = zero4;

#pragma unroll
  for (int t = 0; t < 6; ++t)
    gld_lds16(gsrc[t], &lds2[0][(wv * 64 + t * 512) * 8]);
#pragma unroll
  for (int t = 0; t < 6; ++t)
    gld_lds16(gsrc[t] + 32, &lds2[1][(wv * 64 + t * 512) * 8]);
  asm volatile("s_waitcnt vmcnt(6)" : : : "memory");
  __builtin_amdgcn_s_barrier();

  for (int ks = 0; ks < 32; ++ks) {
    const short* bp = &lds2[ks & 1][0];

    short8 ah[4], wh4[4], al[4], wl4[4];
#pragma unroll
    for (int mi = 0; mi < 4; ++mi) ah[mi] = *(const short8*)(bp + offa[mi]);
#pragma unroll
    for (int ni = 0; ni < 4; ++ni)
      wh4[ni] = *(const short8*)(bp + 16384 + offw[ni]);

    __builtin_amdgcn_s_setprio(1);
#pragma unroll
    for (int mi = 0; mi < 4; ++mi)
#pragma unroll
      for (int ni = 0; ni < 4; ++ni)
        acc[mi][ni] = __builtin_amdgcn_mfma_f32_16x16x32_bf16(
            ah[mi], wh4[ni], acc[mi][ni], 0, 0, 0);

#pragma unroll
    for (int mi = 0; mi < 4; ++mi)
      al[mi] = *(const short8*)(bp + 8192 + offa[mi]);
#pragma unroll
    for (int mi = 0; mi < 4; ++mi)
#pragma unroll
      for (int ni = 0; ni < 4; ++ni)
        acc[mi][ni] = __builtin_amdgcn_mfma_f32_16x16x32_bf16(
            al[mi], wh4[ni], acc[mi][ni], 0, 0, 0);

#pragma unroll
    for (int ni = 0; ni < 4; ++ni)
      wl4[ni] = *(const short8*)(bp + 20480 + offw[ni]);
#pragma unroll
    for (int mi = 0; mi < 4; ++mi)
#pragma unroll
      for (int ni = 0; ni < 4; ++ni)
        acc[mi][ni] = __builtin_amdgcn_mfma_f32_16x16x32_bf16(
            ah[mi], wl4[ni], acc[mi][ni], 0, 0, 0);
    __builtin_amdgcn_s_setprio(0);

    asm volatile("s_waitcnt lgkmcnt(0)" : : : "memory");
    __builtin_amdgcn_sched_barrier(0);
    __builtin_amdgcn_s_barrier();

    if (ks + 2 < 32) {
#pragma unroll
      for (int t = 0; t < 6; ++t)
        gld_lds16(gsrc[t] + (ks + 2) * 32,
                  &lds2[ks & 1][(wv * 64 + t * 512) * 8]);
      asm volatile("s_waitcnt vmcnt(6)" : : : "memory");
    } else {
      asm volatile("s_waitcnt vmcnt(0)" : : : "memory");
    }
    __builtin_amdgcn_s_barrier();
  }

#pragma unroll
  for (int mi = 0; mi < 4; ++mi)
#pragma unroll
    for (int ni = 0; ni < 4; ++ni)
#pragma unroll
      for (int r = 0; r < 4; ++r) {
        int grow = bx * 256 + wm * 64 + mi * 16 + kg * 4 + r;
        int gcol = by * 128 + wn * 64 + ni * 16 + l15;
        G[(size_t)grow * 4096 + gcol] = acc[mi][ni][r];
      }
}

// ---------------- Recurrence (round 12) ----------------
// Round-9 structure (scalar v_fmac matvec — AGPR weights read natively,
// round-10's pk_fma was neutral-negative; readlane h-broadcast; stride-20
// b128 partial exchange; +1-step G prefetch; 1 barrier/step).
// KEY CHANGE: per-step __syncthreads() -> s_waitcnt lgkmcnt(0) + raw
// s_barrier. __syncthreads emits vmcnt(0) too, which forced the out-store
// to retire AND the G(s+1) prefetch to complete at every barrier — the
// ~840 cyc/step latency deficit (same drain stall killed in gemm3, round
// 9). Only LDS (partials) crosses the barrier, so lgkmcnt(0) suffices;
// out-stores have no cross-thread readers; G loads get compiler vmcnt
// waits at their use.
__global__ __launch_bounds__(512, 1)
void recur_kernel(const float* __restrict__ G,     // [32*tch, 4096] chunk
                  const float* __restrict__ Whh,   // [8,512,128]
                  const float* __restrict__ bias,  // [8,512]
                  float* __restrict__ out,         // [32,512,1024]
                  float* __restrict__ state,       // 4 x [32,8,128]
                  int t0, int tch, int first) {
  int blk = blockIdx.x;
  int b = blk >> 3, h = blk & 7;
  int t = threadIdx.x;
  int w = t >> 6;             // wave 0..7
  int l = t & 63;             // lane
  int q = w >> 1;             // col-slice / pair 0..3
  int em = (w & 1) * 64 + l;  // matvec output element 0..127
  int eg = q * 32 + (l & 31); // gate element this thread maintains

  __shared__ __align__(16) float part[2][128 * 20];  // 20 KB

  // weights: wreg[g*32+c] = Whh[h][g*128+em][32q+c]
  float wreg[128];
  {
    const float* wb = Whh + (size_t)h * 65536 + (size_t)q * 32;
#pragma unroll
    for (int g = 0; g < 4; ++g) {
      const float4* wp = (const float4*)(wb + (size_t)(g * 128 + em) * 128);
#pragma unroll
      for (int c4 = 0; c4 < 8; ++c4) {
        float4 v = wp[c4];
        wreg[g * 32 + c4 * 4 + 0] = v.x;
        wreg[g * 32 + c4 * 4 + 1] = v.y;
        wreg[g * 32 + c4 * 4 + 2] = v.z;
        wreg[g * 32 + c4 * 4 + 3] = v.w;
      }
    }
  }
#pragma unroll
  for (int i = 0; i < 128; ++i)
    asm volatile("" : "+v"(wreg[i]));  // opaque def: keep resident

  int si = (b * 8 + h) * 128 + eg;
  float hreg = 0.f, c_r = 0.f, n_r = 0.f, m_r = 0.f;
  if (!first) {
    hreg = state[si];
    c_r = state[32768 + si];
    m_r = state[65536 + si];
    n_r = state[98304 + si];
  }
  float bj0 = bias[h * 512 + eg];
  float bj1 = bias[h * 512 + 128 + eg];
  float bj2 = bias[h * 512 + 256 + eg];
  float bj3 = bias[h * 512 + 384 + eg];

  const float* gpb = G + (size_t)(b * tch) * 4096 + h * 512 + eg;
  float* op = out + ((size_t)b * 512 + t0) * 1024 + h * 128 + eg;
  bool writer = ((w & 1) == 0) && (l < 32);

  int ebase = em * 20 + q * 4;   // write slot
  int rb0 = eg * 20 + 0;
  int rb1 = eg * 20 + 4;
  int rb2 = eg * 20 + 8;
  int rb3 = eg * 20 + 12;

  // G for step 0 (exposed once; later steps prefetched +1 ahead)
  float g0 = gpb[0], g1 = gpb[128], g2 = gpb[256], g3 = gpb[384];

  for (int s = 0; s < tch; ++s) {
    // prefetch G for step s+1 (consumed at END of iteration s+1; with the
    // raw barrier below it genuinely stays in flight a full step now)
    float gn0 = 0.f, gn1 = 0.f, gn2 = 0.f, gn3 = 0.f;
    if (s + 1 < tch) {
      const float* gr = gpb + (size_t)(s + 1) * 4096;
      gn0 = gr[0]; gn1 = gr[128]; gn2 = gr[256]; gn3 = gr[384];
    }

    // ---- matvec: h broadcast via readlane (VALU), no LDS ----
    float a0 = 0.f, a1 = 0.f, a2 = 0.f, a3 = 0.f;
    int hbits = __float_as_int(hreg);
#pragma unroll
    for (int c = 0; c < 32; ++c) {
      float hs = __int_as_float(__builtin_amdgcn_readlane(hbits, c));
      a0 = fmaf(wreg[c], hs, a0);
      a1 = fmaf(wreg[32 + c], hs, a1);
      a2 = fmaf(wreg[64 + c], hs, a2);
      a3 = fmaf(wreg[96 + c], hs, a3);
    }
    float4 pv = {a0, a1, a2, a3};
    *(float4*)&part[s & 1][ebase] = pv;

    // barrier: only LDS must be visible across it (lgkm), NOT vmem
    asm volatile("s_waitcnt lgkmcnt(0)" : : : "memory");
    __builtin_amdgcn_sched_barrier(0);
    __builtin_amdgcn_s_barrier();

    // ---- gate: all waves, redundant per (lane-half x pair) ----
    float4 p0 = *(const float4*)&part[s & 1][rb0];
    float4 p1 = *(const float4*)&part[s & 1][rb1];
    float4 p2 = *(const float4*)&part[s & 1][rb2];
    float4 p3 = *(const float4*)&part[s & 1][rb3];
    float iv = bj0 + g0 + ((p0.x + p1.x) + (p2.x + p3.x));
    float fv = bj1 + g1 + ((p0.y + p1.y) + (p2.y + p3.y));
    float zv = bj2 + g2 + ((p0.z + p1.z) + (p2.z + p3.z));
    float ov = bj3 + g3 + ((p0.w + p1.w) + (p2.w + p3.w));
    float e2 = __expf(2.f * zv);
    float zt = 1.f - 2.f * __builtin_amdgcn_rcpf(e2 + 1.f);   // tanh
    float og = __builtin_amdgcn_rcpf(1.f + __expf(-ov));      // sigmoid
    float mn = fmaxf(fv + m_r, iv);
    float ie = __expf(iv - mn);
    float fe = __expf(fv + m_r - mn);
    c_r = fe * c_r + ie * zt;
    n_r = fe * n_r + ie;
    m_r = mn;
    float hnew = og * c_r * __builtin_amdgcn_rcpf(n_r);
    hreg = hnew;
    if (writer) op[(size_t)s * 1024] = hnew;
    g0 = gn0; g1 = gn1; g2 = gn2; g3 = gn3;
    // no second barrier: next step writes the OTHER part buffer; write(s+2)
    // to this buffer happens after barrier(s+1), by which point every
    // thread has consumed its read(s) (reads are waited at use, in-order
    // per thread, before reaching barrier(s+1)).
  }

  if (writer) {
    state[si] = hreg;
    state[32768 + si] = c_r;
    state[65536 + si] = m_r;
    state[98304 + si] = n_r;
  }
}

// ---------------- launch ----------------
extern "C" void kernel_launch(void* const* d_in, const int* in_sizes, int n_in,
                              void* d_out, int out_size, void* d_ws, size_t ws_size,
                              hipStream_t stream) {
  const float* xs   = (const float*)d_in[0];
  const float* wif  = (const float*)d_in[1];
  const float* wzo  = (const float*)d_in[2];
  const float* whh  = (const float*)d_in[3];
  const float* bias = (const float*)d_in[4];
  float* out = (float*)d_out;

  char* ws = (char*)d_ws;
  unsigned short* Ahi = (unsigned short*)ws;                 // 33,554,432 B
  unsigned short* Alo = (unsigned short*)(ws + 33554432);    // 33,554,432 B
  unsigned short* Whi = (unsigned short*)(ws + 67108864);    //  8,388,608 B
  unsigned short* Wlo = (unsigned short*)(ws + 75497472);    //  8,388,608 B
  const size_t gbase = 83886080;

  // adaptive time chunk so G fits in ws
  int tch = 512;
  while (tch > 8 &&
         gbase + (size_t)32 * tch * 4096 * 4 + 524288 > ws_size)
    tch >>= 1;
  int ltch = 0;
  while ((1 << (ltch + 1)) <= tch) ++ltch;

  float* G = (float*)(ws + gbase);
  float* state = (float*)(ws + gbase + (size_t)32 * tch * 4096 * 4);

  conv_x_split<<<16384, 256, 0, stream>>>(xs, Ahi, Alo, 4194304);
  conv_w_split<<<4096, 256, 0, stream>>>(wif, wzo, Whi, Wlo);

  for (int t0 = 0; t0 < 512; t0 += tch) {
    gemm3_kernel<<<dim3((32 * tch) / 256, 32), 512, 0, stream>>>(
        Ahi, Alo, Whi, Wlo, G, t0, ltch);
    recur_kernel<<<256, 512, 0, stream>>>(G, whh, bias, out, state, t0, tch,
                                          t0 == 0);
  }
}